// Round 7
// baseline (23.331 us; speedup 1.0000x reference)
//
#include <hip/hip_runtime.h>
#include <cmath>

// Problem constants
#define NB      256       // batch rows
#define RPW     2         // rows per wave
#define SMOOTHI (1.0f/1.5f)
#define CONVEX  0.5f
#define MAXN    32        // iteration cap
#define ALPHA0  0.75f     // first step (spectrum of J in [2/3, ~2.6])
#define EXIT_N2 2.5e-4f   // ||r||<=1.6e-2 -> ||x-x*||<=2.4e-2 (thr 0.1475)

// ---- VALU butterfly reductions (DPP + permlane); DS pipe only for xor16 ----
template<int CTRL>
__device__ __forceinline__ float dpp_add(float v) {
  int s = __builtin_amdgcn_update_dpp(0, __float_as_int(v), CTRL, 0xF, 0xF, true);
  return v + __int_as_float(s);
}

__device__ __forceinline__ float rowsum16(float v) {
  v = dpp_add<0xB1>(v);    // quad_perm {1,0,3,2} : xor1
  v = dpp_add<0x4E>(v);    // quad_perm {2,3,0,1} : xor2
  v = dpp_add<0x141>(v);   // row_half_mirror     : joins 4-blocks
  v = dpp_add<0x140>(v);   // row_mirror          : joins 8-blocks
  return v;
}

__device__ __forceinline__ float xadd16(float v) {   // v + v[lane^16]
  return v + __int_as_float(
      __builtin_amdgcn_ds_swizzle(__float_as_int(v), 0x401F));
}

__device__ __forceinline__ float xadd32(float v) {   // v + v[lane^32]
  int x = __float_as_int(v);
  auto r = __builtin_amdgcn_permlane32_swap(x, x, false, false);
  return __int_as_float(r[0]) + __int_as_float(r[1]);
}

__device__ __forceinline__ float wsum64f(float v) {
  return xadd32(xadd16(rowsum16(v)));
}

// branchless sigmoid + softplus on native v_exp/v_log/v_rcp
__device__ __forceinline__ void sig_sp(float x, float& sg, float& sp) {
  float t   = __expf(-fabsf(x));
  float inv = __builtin_amdgcn_rcpf(1.0f + t);
  sg = (x >= 0.0f) ? inv : t * inv;
  sp = fmaxf(x, 0.0f) + __logf(1.0f + t);
}

__device__ __forceinline__ float sigmoidf_(float x) {
  float t   = __expf(-fabsf(x));
  float inv = __builtin_amdgcn_rcpf(1.0f + t);
  return (x >= 0.0f) ? inv : t * inv;
}

// One wave per TWO rows (shared weight registers, duplicated tiny state):
// two independent dependency chains give the scheduler ILP to hide LDS and
// transcendental latency. BB2 Richardson, per-row early exit + argmin net.
__global__ __launch_bounds__(64, 1)
void blnn_solve(const float* __restrict__ zg,
                const float* __restrict__ W0g, const float* __restrict__ b0g,
                const float* __restrict__ W1g, const float* __restrict__ b1g,
                const float* __restrict__ Wz1g,
                const float* __restrict__ W2g, const float* __restrict__ b2g,
                const float* __restrict__ Wz2g,
                float* __restrict__ outg) {
  const int lane = threadIdx.x;            // 0..63
  const int r0   = blockIdx.x * RPW;       // rows r0, r0+1
  const int i16  = lane & 15;
  const int c4   = lane >> 4;

  __shared__ __align__(16) float sh2[RPW][64];
  __shared__ __align__(16) float svv[RPW][64];
  __shared__ __align__(16) float sww[RPW][64];

  // ---- loop-invariant weights into registers (shared by both rows) ----
  float w0row[16], w1row[16], w0d[16], w1d[16];
#pragma unroll
  for (int q = 0; q < 4; ++q) {
    float4 a = *reinterpret_cast<const float4*>(&W0g[lane * 16 + 4 * q]);
    float4 b = *reinterpret_cast<const float4*>(&W1g[lane * 16 + 4 * q]);
    w0row[4*q+0] = a.x; w0row[4*q+1] = a.y; w0row[4*q+2] = a.z; w0row[4*q+3] = a.w;
    w1row[4*q+0] = b.x; w1row[4*q+1] = b.y; w1row[4*q+2] = b.z; w1row[4*q+3] = b.w;
  }
#pragma unroll
  for (int h = 0; h < 16; ++h) {
    w0d[h] = W0g[(c4 * 16 + h) * 16 + i16];
    w1d[h] = W1g[(c4 * 16 + h) * 16 + i16];
  }
  float wz1row[64], wz1col[64];
#pragma unroll
  for (int t = 0; t < 16; ++t) {
    float4 r4 = *reinterpret_cast<const float4*>(&Wz1g[lane * 64 + 4 * t]);
    wz1row[4*t+0] = fmaxf(r4.x, 0.0f);
    wz1row[4*t+1] = fmaxf(r4.y, 0.0f);
    wz1row[4*t+2] = fmaxf(r4.z, 0.0f);
    wz1row[4*t+3] = fmaxf(r4.w, 0.0f);
  }
#pragma unroll
  for (int j = 0; j < 64; ++j)
    wz1col[j] = fmaxf(Wz1g[j * 64 + lane], 0.0f);
  float w2r[16];
#pragma unroll
  for (int i = 0; i < 16; ++i) w2r[i] = W2g[i];
  const float b0r  = b0g[lane];
  const float b1r  = b1g[lane];
  const float wz2r = fmaxf(Wz2g[lane], 0.0f);
  const float b2r  = b2g[0];
  const float w2i  = W2g[i16];
  const float ziA  = zg[(r0 + 0) * 16 + i16];
  const float ziB  = zg[(r0 + 1) * 16 + i16];

  // per-row solver state (tiny)
  float xiA = 1.0f, xiB = 1.0f;
  float rprevA = 0.f, rprevB = 0.f;
  float aprevA = ALPHA0, aprevB = ALPHA0;
  float pn2A = 1e30f, pn2B = 1e30f;
  float bn2A = 1e30f, bn2B = 1e30f;
  float xbA = 1.0f, xbB = 1.0f;
  bool  dA = false, dB = false;

#pragma unroll 1
  for (int it = 0; it < MAXN; ++it) {
    if (dA && dB) break;                    // wave-uniform

    // broadcast x for both rows via readlane (wave-uniform scalars)
    float xsA[16], xsB[16];
#pragma unroll
    for (int i = 0; i < 16; ++i) {
      xsA[i] = __int_as_float(__builtin_amdgcn_readlane(__float_as_int(xiA), i));
      xsB[i] = __int_as_float(__builtin_amdgcn_readlane(__float_as_int(xiB), i));
    }

    // ---- phase A (both rows): pre0[h], h = lane ----
    float aA0 = b0r, aA1 = 0.f, aA2 = 0.f, aA3 = 0.f;
    float aB0 = b0r, aB1 = 0.f, aB2 = 0.f, aB3 = 0.f;
#pragma unroll
    for (int i = 0; i < 16; i += 4) {
      aA0 = fmaf(w0row[i + 0], xsA[i + 0], aA0);
      aA1 = fmaf(w0row[i + 1], xsA[i + 1], aA1);
      aA2 = fmaf(w0row[i + 2], xsA[i + 2], aA2);
      aA3 = fmaf(w0row[i + 3], xsA[i + 3], aA3);
      aB0 = fmaf(w0row[i + 0], xsB[i + 0], aB0);
      aB1 = fmaf(w0row[i + 1], xsB[i + 1], aB1);
      aB2 = fmaf(w0row[i + 2], xsB[i + 2], aB2);
      aB3 = fmaf(w0row[i + 3], xsB[i + 3], aB3);
    }
    float s0A, sp0A, s0B, sp0B;
    sig_sp((aA0 + aA1) + (aA2 + aA3), s0A, sp0A);
    sig_sp((aB0 + aB1) + (aB2 + aB3), s0B, sp0B);
    sh2[0][lane] = sp0A;
    sh2[1][lane] = sp0B;

    // ---- phase B (both rows): pre1[o], o = lane ----
    float cA0 = b1r, cA1 = 0.f, cA2 = 0.f, cA3 = 0.f;
    float cB0 = b1r, cB1 = 0.f, cB2 = 0.f, cB3 = 0.f;
#pragma unroll
    for (int i = 0; i < 16; i += 4) {
      cA0 = fmaf(w1row[i + 0], xsA[i + 0], cA0);
      cA1 = fmaf(w1row[i + 1], xsA[i + 1], cA1);
      cA2 = fmaf(w1row[i + 2], xsA[i + 2], cA2);
      cA3 = fmaf(w1row[i + 3], xsA[i + 3], cA3);
      cB0 = fmaf(w1row[i + 0], xsB[i + 0], cB0);
      cB1 = fmaf(w1row[i + 1], xsB[i + 1], cB1);
      cB2 = fmaf(w1row[i + 2], xsB[i + 2], cB2);
      cB3 = fmaf(w1row[i + 3], xsB[i + 3], cB3);
    }
#pragma unroll
    for (int h = 0; h < 64; h += 4) {
      float4 hA = *reinterpret_cast<const float4*>(&sh2[0][h]);
      float4 hB = *reinterpret_cast<const float4*>(&sh2[1][h]);
      cA0 = fmaf(wz1row[h + 0], hA.x, cA0);
      cA1 = fmaf(wz1row[h + 1], hA.y, cA1);
      cA2 = fmaf(wz1row[h + 2], hA.z, cA2);
      cA3 = fmaf(wz1row[h + 3], hA.w, cA3);
      cB0 = fmaf(wz1row[h + 0], hB.x, cB0);
      cB1 = fmaf(wz1row[h + 1], hB.y, cB1);
      cB2 = fmaf(wz1row[h + 2], hB.z, cB2);
      cB3 = fmaf(wz1row[h + 3], hB.w, cB3);
    }
    float sig1A, sp1A, sig1B, sp1B;
    sig_sp((cA0 + cA1) + (cA2 + cA3), sig1A, sp1A);
    sig_sp((cB0 + cB1) + (cB2 + cB3), sig1B, sp1B);
    const float vA = wz2r * sig1A;
    const float vB = wz2r * sig1B;
    svv[0][lane] = vA;
    svv[1][lane] = vB;

    // pre2 path (both rows; independent reduction chains)
    const float p2A = wsum64f(sp1A * wz2r);
    const float p2B = wsum64f(sp1B * wz2r);
    float xw2A = 0.f, xw2B = 0.f;
#pragma unroll
    for (int i = 0; i < 16; ++i) {
      xw2A = fmaf(w2r[i], xsA[i], xw2A);
      xw2B = fmaf(w2r[i], xsB[i], xw2B);
    }
    const float sig2A = sigmoidf_(p2A + xw2A + b2r);
    const float sig2B = sigmoidf_(p2B + xw2B + b2r);

    // ---- phase C (both rows): u[h] = sum_o v[o]*Wz1p[o,h] ----
    float uA0 = 0.f, uA1 = 0.f, uA2 = 0.f, uA3 = 0.f;
    float uB0 = 0.f, uB1 = 0.f, uB2 = 0.f, uB3 = 0.f;
#pragma unroll
    for (int o = 0; o < 64; o += 4) {
      float4 vA4 = *reinterpret_cast<const float4*>(&svv[0][o]);
      float4 vB4 = *reinterpret_cast<const float4*>(&svv[1][o]);
      uA0 = fmaf(wz1col[o + 0], vA4.x, uA0);
      uA1 = fmaf(wz1col[o + 1], vA4.y, uA1);
      uA2 = fmaf(wz1col[o + 2], vA4.z, uA2);
      uA3 = fmaf(wz1col[o + 3], vA4.w, uA3);
      uB0 = fmaf(wz1col[o + 0], vB4.x, uB0);
      uB1 = fmaf(wz1col[o + 1], vB4.y, uB1);
      uB2 = fmaf(wz1col[o + 2], vB4.z, uB2);
      uB3 = fmaf(wz1col[o + 3], vB4.w, uB3);
    }
    sww[0][lane] = ((uA0 + uA1) + (uA2 + uA3)) * s0A;
    sww[1][lane] = ((uB0 + uB1) + (uB2 + uB3)) * s0B;

    // ---- phase D (both rows): g[i16] ----
    float gA0 = 0.f, gA1 = 0.f, gB0 = 0.f, gB1 = 0.f;
#pragma unroll
    for (int t = 0; t < 4; ++t) {
      float4 wA4 = *reinterpret_cast<const float4*>(&sww[0][c4 * 16 + 4 * t]);
      float4 vA4 = *reinterpret_cast<const float4*>(&svv[0][c4 * 16 + 4 * t]);
      float4 wB4 = *reinterpret_cast<const float4*>(&sww[1][c4 * 16 + 4 * t]);
      float4 vB4 = *reinterpret_cast<const float4*>(&svv[1][c4 * 16 + 4 * t]);
      gA0 = fmaf(wA4.x, w0d[4 * t + 0], gA0);
      gA0 = fmaf(wA4.y, w0d[4 * t + 1], gA0);
      gA0 = fmaf(wA4.z, w0d[4 * t + 2], gA0);
      gA0 = fmaf(wA4.w, w0d[4 * t + 3], gA0);
      gA1 = fmaf(vA4.x, w1d[4 * t + 0], gA1);
      gA1 = fmaf(vA4.y, w1d[4 * t + 1], gA1);
      gA1 = fmaf(vA4.z, w1d[4 * t + 2], gA1);
      gA1 = fmaf(vA4.w, w1d[4 * t + 3], gA1);
      gB0 = fmaf(wB4.x, w0d[4 * t + 0], gB0);
      gB0 = fmaf(wB4.y, w0d[4 * t + 1], gB0);
      gB0 = fmaf(wB4.z, w0d[4 * t + 2], gB0);
      gB0 = fmaf(wB4.w, w0d[4 * t + 3], gB0);
      gB1 = fmaf(vB4.x, w1d[4 * t + 0], gB1);
      gB1 = fmaf(vB4.y, w1d[4 * t + 1], gB1);
      gB1 = fmaf(vB4.z, w1d[4 * t + 2], gB1);
      gB1 = fmaf(vB4.w, w1d[4 * t + 3], gB1);
    }
    const float gA = xadd32(xadd16(gA0 + gA1));
    const float gB = xadd32(xadd16(gB0 + gB1));

    const float residA = ziA - fmaf(sig2A, gA + w2i, xiA * SMOOTHI);
    const float residB = ziB - fmaf(sig2B, gB + w2i, xiB * SMOOTHI);

    // per-row dots (4 independent DPP chains)
    const float n2A  = rowsum16(residA * residA);
    const float rrpA = rowsum16(residA * rprevA);
    const float n2B  = rowsum16(residB * residB);
    const float rrpB = rowsum16(residB * rprevB);

    if (!dA) {                               // wave-uniform guard
      float alpha;
      if (it == 0) {
        alpha = ALPHA0;
      } else {
        const float sy = aprevA * (pn2A - rrpA);
        const float yy = fmaxf(pn2A - 2.0f * rrpA + n2A, 1e-20f);
        alpha = fminf(fmaxf(sy * __builtin_amdgcn_rcpf(yy), 0.2f), 1.2f);
        if (n2A > pn2A) alpha = fminf(alpha, 0.4f);
      }
      if (n2A < bn2A) { bn2A = n2A; xbA = xiA; }
      xiA    = fmaf(alpha, residA, xiA);
      rprevA = residA; aprevA = alpha; pn2A = n2A;
      if (n2A < EXIT_N2) { dA = true; xbA = xiA; }
    }
    if (!dB) {
      float alpha;
      if (it == 0) {
        alpha = ALPHA0;
      } else {
        const float sy = aprevB * (pn2B - rrpB);
        const float yy = fmaxf(pn2B - 2.0f * rrpB + n2B, 1e-20f);
        alpha = fminf(fmaxf(sy * __builtin_amdgcn_rcpf(yy), 0.2f), 1.2f);
        if (n2B > pn2B) alpha = fminf(alpha, 0.4f);
      }
      if (n2B < bn2B) { bn2B = n2B; xbB = xiB; }
      xiB    = fmaf(alpha, residB, xiB);
      rprevB = residB; aprevB = alpha; pn2B = n2B;
      if (n2B < EXIT_N2) { dB = true; xbB = xiB; }
    }
  }

  if (lane < 16) {
    outg[(r0 + 0) * 16 + lane] = fmaf(CONVEX, ziA, xbA);
    outg[(r0 + 1) * 16 + lane] = fmaf(CONVEX, ziB, xbB);
  }
}

extern "C" void kernel_launch(void* const* d_in, const int* in_sizes, int n_in,
                              void* d_out, int out_size, void* d_ws, size_t ws_size,
                              hipStream_t stream) {
  const float* z   = (const float*)d_in[0];
  const float* W0  = (const float*)d_in[1];
  const float* b0  = (const float*)d_in[2];
  const float* W1  = (const float*)d_in[3];
  const float* b1  = (const float*)d_in[4];
  const float* Wz1 = (const float*)d_in[5];
  const float* W2  = (const float*)d_in[6];
  const float* b2  = (const float*)d_in[7];
  const float* Wz2 = (const float*)d_in[8];
  float* out = (float*)d_out;

  blnn_solve<<<dim3(NB / RPW), dim3(64), 0, stream>>>(
      z, W0, b0, W1, b1, Wz1, W2, b2, Wz2, out);
}

// Round 8
// 13.370 us; speedup vs baseline: 1.7450x; 1.7450x over previous
//
#include <hip/hip_runtime.h>
#include <cmath>

// Problem constants
#define NB      256       // batch rows
#define SMOOTHI (1.0f/1.5f)
#define CONVEX  0.5f
#define MAXN    32        // iteration cap
#define ALPHA0  0.75f     // first step (spectrum of J in [2/3, ~2.6])
#define EXIT_N2 2.5e-4f   // ||r||<=1.6e-2 -> ||x-x*||<=2.4e-2 (thr 0.1475)

// ---- VALU butterfly reductions (DPP + permlane) ----
template<int CTRL>
__device__ __forceinline__ float dpp_add(float v) {
  int s = __builtin_amdgcn_update_dpp(0, __float_as_int(v), CTRL, 0xF, 0xF, true);
  return v + __int_as_float(s);
}

// full sum within each 16-lane row
__device__ __forceinline__ float rowsum16(float v) {
  v = dpp_add<0xB1>(v);    // quad_perm {1,0,3,2} : xor1
  v = dpp_add<0x4E>(v);    // quad_perm {2,3,0,1} : xor2
  v = dpp_add<0x141>(v);   // row_half_mirror     : joins 4-blocks
  v = dpp_add<0x140>(v);   // row_mirror          : joins 8-blocks
  return v;
}

__device__ __forceinline__ float xadd16(float v) {   // v + v[lane^16]
#if __has_builtin(__builtin_amdgcn_permlane16_swap)
  int x = __float_as_int(v);
  auto r = __builtin_amdgcn_permlane16_swap(x, x, false, false);
  return __int_as_float(r[0]) + __int_as_float(r[1]);
#else
  return v + __int_as_float(
      __builtin_amdgcn_ds_swizzle(__float_as_int(v), 0x401F));
#endif
}

__device__ __forceinline__ float xadd32(float v) {   // v + v[lane^32]
  int x = __float_as_int(v);
  auto r = __builtin_amdgcn_permlane32_swap(x, x, false, false);
  return __int_as_float(r[0]) + __int_as_float(r[1]);
}

__device__ __forceinline__ float wsum64f(float v) {
  return xadd32(xadd16(rowsum16(v)));
}

// branchless sigmoid + softplus on native v_exp/v_log/v_rcp
__device__ __forceinline__ void sig_sp(float x, float& sg, float& sp) {
  float t   = __expf(-fabsf(x));
  float inv = __builtin_amdgcn_rcpf(1.0f + t);
  sg = (x >= 0.0f) ? inv : t * inv;
  sp = fmaxf(x, 0.0f) + __logf(1.0f + t);
}

__device__ __forceinline__ float sigmoidf_(float x) {
  float t   = __expf(-fabsf(x));
  float inv = __builtin_amdgcn_rcpf(1.0f + t);
  return (x >= 0.0f) ? inv : t * inv;
}

// One wave per row, 256 independent blocks, no grid sync.
// Alternating-BB (BB1/BB2) Richardson on f1(x)=z (J = H + I/1.5 SPD),
// growth safeguard + argmin-iterate net, early exit at ||r||^2 < 2.5e-4.
__global__ __launch_bounds__(64, 1)
void blnn_solve(const float* __restrict__ zg,
                const float* __restrict__ W0g, const float* __restrict__ b0g,
                const float* __restrict__ W1g, const float* __restrict__ b1g,
                const float* __restrict__ Wz1g,
                const float* __restrict__ W2g, const float* __restrict__ b2g,
                const float* __restrict__ Wz2g,
                float* __restrict__ outg) {
  const int lane = threadIdx.x;     // 0..63
  const int row  = blockIdx.x;      // 0..255
  const int i16  = lane & 15;
  const int c4   = lane >> 4;

  __shared__ __align__(16) float sh2[64];
  __shared__ __align__(16) float svv[64];
  __shared__ __align__(16) float sww[64];

  // ---- loop-invariant weights into registers ----
  float w0row[16], w1row[16], w0d[16], w1d[16];
#pragma unroll
  for (int q = 0; q < 4; ++q) {
    float4 a = *reinterpret_cast<const float4*>(&W0g[lane * 16 + 4 * q]);
    float4 b = *reinterpret_cast<const float4*>(&W1g[lane * 16 + 4 * q]);
    w0row[4*q+0] = a.x; w0row[4*q+1] = a.y; w0row[4*q+2] = a.z; w0row[4*q+3] = a.w;
    w1row[4*q+0] = b.x; w1row[4*q+1] = b.y; w1row[4*q+2] = b.z; w1row[4*q+3] = b.w;
  }
#pragma unroll
  for (int h = 0; h < 16; ++h) {    // L1 hits after the row pass
    w0d[h] = W0g[(c4 * 16 + h) * 16 + i16];
    w1d[h] = W1g[(c4 * 16 + h) * 16 + i16];
  }
  float wz1row[64], wz1col[64];
#pragma unroll
  for (int t = 0; t < 16; ++t) {
    float4 r4 = *reinterpret_cast<const float4*>(&Wz1g[lane * 64 + 4 * t]);
    wz1row[4*t+0] = fmaxf(r4.x, 0.0f);
    wz1row[4*t+1] = fmaxf(r4.y, 0.0f);
    wz1row[4*t+2] = fmaxf(r4.z, 0.0f);
    wz1row[4*t+3] = fmaxf(r4.w, 0.0f);
  }
#pragma unroll
  for (int j = 0; j < 64; ++j)      // coalesced per-j
    wz1col[j] = fmaxf(Wz1g[j * 64 + lane], 0.0f);
  float w2r[16];
#pragma unroll
  for (int i = 0; i < 16; ++i) w2r[i] = W2g[i];   // uniform
  const float b0r  = b0g[lane];
  const float b1r  = b1g[lane];
  const float wz2r = fmaxf(Wz2g[lane], 0.0f);
  const float b2r  = b2g[0];
  const float w2i  = W2g[i16];
  const float zi   = zg[row * 16 + i16];

  float xi      = 1.0f;     // this lane's x element (i = i16)
  float rprev   = 0.0f;
  float aprev   = ALPHA0;
  float prev_n2 = 1e30f;
  float best_n2 = 1e30f;
  float xb      = 1.0f;     // argmin-residual iterate

#pragma unroll 1
  for (int it = 0; it < MAXN; ++it) {
    if (prev_n2 < EXIT_N2) { xb = xi; break; }   // wave-uniform

    // broadcast x via readlane -> wave-uniform scalars
    float xs[16];
#pragma unroll
    for (int i = 0; i < 16; ++i)
      xs[i] = __int_as_float(__builtin_amdgcn_readlane(__float_as_int(xi), i));

    // ---- phase A: pre0[h], h = lane ----
    float a0 = b0r, a1 = 0.f, a2 = 0.f, a3 = 0.f;
#pragma unroll
    for (int i = 0; i < 16; i += 4) {
      a0 = fmaf(w0row[i + 0], xs[i + 0], a0);
      a1 = fmaf(w0row[i + 1], xs[i + 1], a1);
      a2 = fmaf(w0row[i + 2], xs[i + 2], a2);
      a3 = fmaf(w0row[i + 3], xs[i + 3], a3);
    }
    const float pre0 = (a0 + a1) + (a2 + a3);
    float s0, sp0;
    sig_sp(pre0, s0, sp0);
    sh2[lane] = sp0;

    // ---- phase B: pre1[o], o = lane ----
    float c0 = b1r, c1 = 0.f, c2 = 0.f, c3 = 0.f;
#pragma unroll
    for (int i = 0; i < 16; i += 4) {
      c0 = fmaf(w1row[i + 0], xs[i + 0], c0);
      c1 = fmaf(w1row[i + 1], xs[i + 1], c1);
      c2 = fmaf(w1row[i + 2], xs[i + 2], c2);
      c3 = fmaf(w1row[i + 3], xs[i + 3], c3);
    }
#pragma unroll
    for (int h = 0; h < 64; h += 4) {
      float4 hv = *reinterpret_cast<const float4*>(&sh2[h]);
      c0 = fmaf(wz1row[h + 0], hv.x, c0);
      c1 = fmaf(wz1row[h + 1], hv.y, c1);
      c2 = fmaf(wz1row[h + 2], hv.z, c2);
      c3 = fmaf(wz1row[h + 3], hv.w, c3);
    }
    const float pre1 = (c0 + c1) + (c2 + c3);
    float sig1, sp1;
    sig_sp(pre1, sig1, sp1);
    const float v = wz2r * sig1;
    svv[lane] = v;

    // pre2 path (resolves in parallel with phases C/D)
    const float p2 = wsum64f(sp1 * wz2r);
    float xw2 = 0.f;
#pragma unroll
    for (int i = 0; i < 16; ++i) xw2 = fmaf(w2r[i], xs[i], xw2);
    const float sig2 = sigmoidf_(p2 + xw2 + b2r);

    // ---- phase C: u[h] = sum_o v[o]*Wz1p[o,h], h = lane ----
    float u0 = 0.f, u1 = 0.f, u2 = 0.f, u3 = 0.f;
#pragma unroll
    for (int o = 0; o < 64; o += 4) {
      float4 vv = *reinterpret_cast<const float4*>(&svv[o]);
      u0 = fmaf(wz1col[o + 0], vv.x, u0);
      u1 = fmaf(wz1col[o + 1], vv.y, u1);
      u2 = fmaf(wz1col[o + 2], vv.z, u2);
      u3 = fmaf(wz1col[o + 3], vv.w, u3);
    }
    sww[lane] = ((u0 + u1) + (u2 + u3)) * s0;

    // ---- phase D: g[i16] = sum_h w[h]*W0[h,i] + sum_o v[o]*W1[o,i] ----
    float g0 = 0.f, g1 = 0.f;
#pragma unroll
    for (int t = 0; t < 4; ++t) {
      float4 wv4 = *reinterpret_cast<const float4*>(&sww[c4 * 16 + 4 * t]);
      float4 vv4 = *reinterpret_cast<const float4*>(&svv[c4 * 16 + 4 * t]);
      g0 = fmaf(wv4.x, w0d[4 * t + 0], g0);
      g0 = fmaf(wv4.y, w0d[4 * t + 1], g0);
      g0 = fmaf(wv4.z, w0d[4 * t + 2], g0);
      g0 = fmaf(wv4.w, w0d[4 * t + 3], g0);
      g1 = fmaf(vv4.x, w1d[4 * t + 0], g1);
      g1 = fmaf(vv4.y, w1d[4 * t + 1], g1);
      g1 = fmaf(vv4.z, w1d[4 * t + 2], g1);
      g1 = fmaf(vv4.w, w1d[4 * t + 3], g1);
    }
    const float g = xadd32(xadd16(g0 + g1));   // VALU-only cross-chunk sum

    const float f1v   = fmaf(sig2, g + w2i, xi * SMOOTHI);
    const float resid = zi - f1v;

    // per-row dots (two independent 4-step DPP chains)
    const float n2  = rowsum16(resid * resid);   // ||r_k||^2
    const float rrp = rowsum16(resid * rprev);   // r_k . r_{k-1}

    // Alternating BB: odd -> BB1 = s.s/s.y, even -> BB2 = s.y/y.y
    float alpha;
    if (it == 0) {
      alpha = ALPHA0;
    } else {
      const float sy = prev_n2 - rrp;            // (s.y)/aprev
      if (it & 1) {
        alpha = aprev * prev_n2 * __builtin_amdgcn_rcpf(fmaxf(sy, 1e-20f));
      } else {
        const float yy = fmaxf(prev_n2 - 2.0f * rrp + n2, 1e-20f);
        alpha = aprev * sy * __builtin_amdgcn_rcpf(yy);
      }
      alpha = fminf(fmaxf(alpha, 0.2f), 1.2f);
      if (n2 > prev_n2) alpha = fminf(alpha, 0.4f);  // growth safeguard
    }

    if (n2 < best_n2) { best_n2 = n2; xb = xi; }

    xi      = fmaf(alpha, resid, xi);
    rprev   = resid;
    aprev   = alpha;
    prev_n2 = n2;
  }

  if (lane < 16) outg[row * 16 + lane] = fmaf(CONVEX, zi, xb);
}

extern "C" void kernel_launch(void* const* d_in, const int* in_sizes, int n_in,
                              void* d_out, int out_size, void* d_ws, size_t ws_size,
                              hipStream_t stream) {
  const float* z   = (const float*)d_in[0];
  const float* W0  = (const float*)d_in[1];
  const float* b0  = (const float*)d_in[2];
  const float* W1  = (const float*)d_in[3];
  const float* b1  = (const float*)d_in[4];
  const float* Wz1 = (const float*)d_in[5];
  const float* W2  = (const float*)d_in[6];
  const float* b2  = (const float*)d_in[7];
  const float* Wz2 = (const float*)d_in[8];
  float* out = (float*)d_out;

  blnn_solve<<<dim3(NB), dim3(64), 0, stream>>>(
      z, W0, b0, W1, b1, Wz1, W2, b2, Wz2, out);
}